// Round 7
// baseline (79.055 us; speedup 1.0000x reference)
//
#include <hip/hip_runtime.h>
#include <math.h>

#define TSTEPS 48
#define FEAT 60
#define BATCH 128
#define BLOCK 512
#define TWO_PI_F 6.2831853071795864769f

// R16: loop issue-count cut.  Same math as R15 (coef[m][243] monomial
// recurrence, packed poly trig).  Changes:
//  (1) selector pk_fmas use VOP3P op_sel to broadcast the trig half in the
//      instruction itself (op_sel_hi:[1,0,1] / op_sel:[0,1,0]) -- removes
//      ~20 splat v_movs per step.
//  (2) 5-chain wave reduction emitted as ONE asm block of interleaved
//      v_add_f32_dpp (single instr per stage, chains 4 apart -> hazard-safe;
//      s_nop guards at block entry/exit).
//  (3) trig as 3 packed pairs {h0,h1},{h2,h3},{h4,h4} (no scalar pipeline).

struct Cf { float r, i; };
__device__ __forceinline__ Cf cmul(Cf a, Cf b){ return {a.r*b.r - a.i*b.i, a.r*b.i + a.i*b.r}; }
__device__ __forceinline__ Cf cadd(Cf a, Cf b){ return {a.r+b.r, a.i+b.i}; }
__device__ __forceinline__ void mm2(const Cf A[4], const Cf B[4], Cf D[4]) {
  D[0] = cadd(cmul(A[0],B[0]), cmul(A[1],B[2]));
  D[1] = cadd(cmul(A[0],B[1]), cmul(A[1],B[3]));
  D[2] = cadd(cmul(A[2],B[0]), cmul(A[3],B[2]));
  D[3] = cadd(cmul(A[2],B[1]), cmul(A[3],B[3]));
}

// fused U = RZ * RY * RX from 3 consecutive params (args in [0,2pi))
__device__ __forceinline__ void fusedU(const float* p, Cf U[4]) {
  float cx = __cosf(0.5f*p[0]), sxn = __sinf(0.5f*p[0]);
  float cy = __cosf(0.5f*p[1]), syn = __sinf(0.5f*p[1]);
  float cz = __cosf(0.5f*p[2]), szn = __sinf(0.5f*p[2]);
  Cf RX[4] = {{cx,0.f},{0.f,-sxn},{0.f,-sxn},{cx,0.f}};
  Cf RY[4] = {{cy,0.f},{-syn,0.f},{syn,0.f},{cy,0.f}};
  Cf RZ[4] = {{cz,-szn},{0.f,0.f},{0.f,0.f},{cz,szn}};
  Cf M[4];
  mm2(RY, RX, M);
  mm2(RZ, M, U);
}

template<int CTRL>
__device__ __forceinline__ float dppf(float v) {
  return __int_as_float(__builtin_amdgcn_mov_dpp(__float_as_int(v), CTRL, 0xF, 0xF, true));
}

template<int M>
__device__ __forceinline__ float sx(float v) {
  if constexpr (M == 1)      return dppf<0xB1>(v);
  else if constexpr (M == 2) return dppf<0x4E>(v);
  else if constexpr (M == 3) return dppf<0x1B>(v);
  else if constexpr (M == 4) return dppf<0x141>(dppf<0x1B>(v));
  else                       return dppf<0x128>(v);   // M == 8
}

template<int M>
__device__ __forceinline__ Cf sxc(Cf v){ return { sx<M>(v.r), sx<M>(v.i) }; }

// ---- packed f32 (VOP3P) ----
typedef float v2f __attribute__((ext_vector_type(2)));
__device__ __forceinline__ v2f pk_fma(v2f a, v2f b, v2f c) {
  v2f d;
  asm("v_pk_fma_f32 %0, %1, %2, %3" : "=v"(d) : "v"(a), "v"(b), "v"(c));
  return d;
}
// d = a * broadcast_lo(b) + c   (both output halves read b's LO half)
__device__ __forceinline__ v2f pk_fma_bl(v2f a, v2f b, v2f c) {
  v2f d;
  asm("v_pk_fma_f32 %0, %1, %2, %3 op_sel:[0,0,0] op_sel_hi:[1,0,1]"
      : "=v"(d) : "v"(a), "v"(b), "v"(c));
  return d;
}
// d = a * broadcast_hi(b) + c   (both output halves read b's HI half)
__device__ __forceinline__ v2f pk_fma_bh(v2f a, v2f b, v2f c) {
  v2f d;
  asm("v_pk_fma_f32 %0, %1, %2, %3 op_sel:[0,1,0] op_sel_hi:[1,1,1]"
      : "=v"(d) : "v"(a), "v"(b), "v"(c));
  return d;
}
__device__ __forceinline__ v2f pk_mul(v2f a, v2f b) {
  v2f d;
  asm("v_pk_mul_f32 %0, %1, %2" : "=v"(d) : "v"(a), "v"(b));
  return d;
}

// 5 independent full-wave sums, one asm block: 6 stages x 5 chains of
// v_add_f32_dpp, interleaved (each chain's ops 4 apart -> DPP wait states
// covered); s_nop guards cover entry (VALU->DPP) and exit (DPP->readlane).
__device__ __forceinline__ void wave_red5(float& r0, float& r1, float& r2,
                                          float& r3, float& r4) {
  asm volatile(
    "s_nop 1\n\t"
    "v_add_f32_dpp %0, %0, %0 row_ror:1 row_mask:0xf bank_mask:0xf\n\t"
    "v_add_f32_dpp %1, %1, %1 row_ror:1 row_mask:0xf bank_mask:0xf\n\t"
    "v_add_f32_dpp %2, %2, %2 row_ror:1 row_mask:0xf bank_mask:0xf\n\t"
    "v_add_f32_dpp %3, %3, %3 row_ror:1 row_mask:0xf bank_mask:0xf\n\t"
    "v_add_f32_dpp %4, %4, %4 row_ror:1 row_mask:0xf bank_mask:0xf\n\t"
    "v_add_f32_dpp %0, %0, %0 row_ror:2 row_mask:0xf bank_mask:0xf\n\t"
    "v_add_f32_dpp %1, %1, %1 row_ror:2 row_mask:0xf bank_mask:0xf\n\t"
    "v_add_f32_dpp %2, %2, %2 row_ror:2 row_mask:0xf bank_mask:0xf\n\t"
    "v_add_f32_dpp %3, %3, %3 row_ror:2 row_mask:0xf bank_mask:0xf\n\t"
    "v_add_f32_dpp %4, %4, %4 row_ror:2 row_mask:0xf bank_mask:0xf\n\t"
    "v_add_f32_dpp %0, %0, %0 row_ror:4 row_mask:0xf bank_mask:0xf\n\t"
    "v_add_f32_dpp %1, %1, %1 row_ror:4 row_mask:0xf bank_mask:0xf\n\t"
    "v_add_f32_dpp %2, %2, %2 row_ror:4 row_mask:0xf bank_mask:0xf\n\t"
    "v_add_f32_dpp %3, %3, %3 row_ror:4 row_mask:0xf bank_mask:0xf\n\t"
    "v_add_f32_dpp %4, %4, %4 row_ror:4 row_mask:0xf bank_mask:0xf\n\t"
    "v_add_f32_dpp %0, %0, %0 row_ror:8 row_mask:0xf bank_mask:0xf\n\t"
    "v_add_f32_dpp %1, %1, %1 row_ror:8 row_mask:0xf bank_mask:0xf\n\t"
    "v_add_f32_dpp %2, %2, %2 row_ror:8 row_mask:0xf bank_mask:0xf\n\t"
    "v_add_f32_dpp %3, %3, %3 row_ror:8 row_mask:0xf bank_mask:0xf\n\t"
    "v_add_f32_dpp %4, %4, %4 row_ror:8 row_mask:0xf bank_mask:0xf\n\t"
    "v_add_f32_dpp %0, %0, %0 row_bcast:15 row_mask:0xf bank_mask:0xf\n\t"
    "v_add_f32_dpp %1, %1, %1 row_bcast:15 row_mask:0xf bank_mask:0xf\n\t"
    "v_add_f32_dpp %2, %2, %2 row_bcast:15 row_mask:0xf bank_mask:0xf\n\t"
    "v_add_f32_dpp %3, %3, %3 row_bcast:15 row_mask:0xf bank_mask:0xf\n\t"
    "v_add_f32_dpp %4, %4, %4 row_bcast:15 row_mask:0xf bank_mask:0xf\n\t"
    "v_add_f32_dpp %0, %0, %0 row_bcast:31 row_mask:0xf bank_mask:0xf\n\t"
    "v_add_f32_dpp %1, %1, %1 row_bcast:31 row_mask:0xf bank_mask:0xf\n\t"
    "v_add_f32_dpp %2, %2, %2 row_bcast:31 row_mask:0xf bank_mask:0xf\n\t"
    "v_add_f32_dpp %3, %3, %3 row_bcast:31 row_mask:0xf bank_mask:0xf\n\t"
    "v_add_f32_dpp %4, %4, %4 row_bcast:31 row_mask:0xf bank_mask:0xf\n\t"
    "s_nop 1"
    : "+v"(r0), "+v"(r1), "+v"(r2), "+v"(r3), "+v"(r4));
}

__device__ __forceinline__ float2 conjmul(float2 a, float2 b) {
  return make_float2(a.x*b.x + a.y*b.y, a.x*b.y - a.y*b.x);   // conj(a)*b
}

// ---- V-build gate helpers (4 amps/thread) ----
template<int M>
__device__ __forceinline__ void lane_u(Cf A[4], const Cf U[4], int hi) {
  Cf ca = hi ? U[3] : U[0];
  Cf cb = hi ? U[2] : U[1];
  #pragma unroll
  for (int r = 0; r < 4; ++r) {
    Cf o = sxc<M>(A[r]);
    A[r] = cadd(cmul(ca, A[r]), cmul(cb, o));
  }
}
template<int M>
__device__ __forceinline__ void lane_crx(Cf A[4], float c, float s, int cv) {
  float cc = cv ? c : 1.f, ss = cv ? s : 0.f;
  #pragma unroll
  for (int r = 0; r < 4; ++r) {
    Cf o = sxc<M>(A[r]);
    A[r] = { cc*A[r].r + ss*o.i, cc*A[r].i - ss*o.r };
  }
}
__device__ __forceinline__ void reg_u_b1(Cf A[4], const Cf U[4]) {
  #pragma unroll
  for (int k = 0; k < 2; ++k) {
    Cf a0 = A[k], a1 = A[k+2];
    A[k]   = cadd(cmul(U[0], a0), cmul(U[1], a1));
    A[k+2] = cadd(cmul(U[2], a0), cmul(U[3], a1));
  }
}
__device__ __forceinline__ void reg_u_b0(Cf A[4], const Cf U[4]) {
  #pragma unroll
  for (int k = 0; k < 4; k += 2) {
    Cf a0 = A[k], a1 = A[k+1];
    A[k]   = cadd(cmul(U[0], a0), cmul(U[1], a1));
    A[k+1] = cadd(cmul(U[2], a0), cmul(U[3], a1));
  }
}
__device__ __forceinline__ void reg_crx_b1(Cf A[4], float c, float s, int cv) {
  float cc = cv ? c : 1.f, ss = cv ? s : 0.f;
  #pragma unroll
  for (int k = 0; k < 2; ++k) {
    Cf a0 = A[k], a1 = A[k+2];
    A[k]   = { cc*a0.r + ss*a1.i, cc*a0.i - ss*a1.r };
    A[k+2] = { ss*a0.i + cc*a1.r, -ss*a0.r + cc*a1.i };
  }
}
__device__ __forceinline__ void reg_crx_b0c1(Cf A[4], float c, float s) {
  Cf a0 = A[2], a1 = A[3];
  A[2] = { c*a0.r + s*a1.i, c*a0.i - s*a1.r };
  A[3] = { s*a0.i + c*a1.r, -s*a0.r + c*a1.i };
}

// generic contraction stage over ALL m: peels current LSB qubit with P.
template<int NTs, int D>
__device__ __forceinline__ void stageK(const float2* __restrict__ src,
                                       float2* __restrict__ dst,
                                       const float2* __restrict__ Pq, int tid) {
  const int total = 5*3*NTs*D*D;
  for (int tau = tid; tau < total; tau += BLOCK) {
    int K = tau % D;
    int J = (tau / D) % D;
    int rest = tau / (D*D);
    int t = rest % NTs;
    int s = (rest / NTs) % 3;
    int m = rest / (3*NTs);
    const float2* Sb = src + (m*NTs + t)*(4*D*D);
    const float2* Pm = Pq + s*4;
    float ax = 0.f, ay = 0.f;
    #pragma unroll
    for (int a = 0; a < 2; ++a)
      #pragma unroll
      for (int bb = 0; bb < 2; ++bb) {
        float2 g = Sb[(2*J+a)*(2*D) + (2*K+bb)];
        float2 p = Pm[bb*2 + a];
        ax += g.x*p.x - g.y*p.y;
        ay += g.x*p.y + g.y*p.x;
      }
    dst[tau] = make_float2(ax, ay);
  }
}

__global__ __launch_bounds__(BLOCK)
void qrnn_kernel(const float* __restrict__ x, const float* __restrict__ hin,
                 const float* __restrict__ params, float* __restrict__ out) {
  __shared__ __align__(16) char bufA[30720];
  __shared__ __align__(16) char bufB[23040];
  __shared__ float coefL[5*256];
  __shared__ float2 Pl[5*12];
  __shared__ float2 U2l[5*4];
  __shared__ float crxcl[8], crxsl[8];
  __shared__ float Wl[6*8];

  const int b   = blockIdx.x;
  const int tid = threadIdx.x;

  float2* Vp  = (float2*)bufB;
  float4* Vp4 = (float4*)bufB;
  float2* A1  = (float2*)bufA;
  float2* A2  = (float2*)bufB;
  float2* A3  = (float2*)bufA;
  float2* A4  = (float2*)bufB;

  // ======= Phase A: small fixed tables — one task group per wave ==========
  if (tid < 5) {                                  // wave 0
    int q = tid;
    Cf U1[4]; fusedU(params + 3*q, U1);
    Cf T[4] = {U1[0], {-U1[1].r,-U1[1].i}, U1[2], {-U1[3].r,-U1[3].i}};
    Cf Ud[4] = {{U1[0].r,-U1[0].i},{U1[2].r,-U1[2].i},
                {U1[1].r,-U1[1].i},{U1[3].r,-U1[3].i}};
    Cf Zt[4]; mm2(T, Ud, Zt);
    Cf Ty[4] = {{-U1[1].i, U1[1].r}, {U1[0].i, -U1[0].r},
                {-U1[3].i, U1[3].r}, {U1[2].i, -U1[2].r}};
    Cf Yt[4]; mm2(Ty, Ud, Yt);
    float2* P = Pl + q*12;
    P[0] = make_float2(1.f,0.f); P[1] = make_float2(0.f,0.f);
    P[2] = make_float2(0.f,0.f); P[3] = make_float2(1.f,0.f);
    #pragma unroll
    for (int e = 0; e < 4; ++e) P[4+e] = make_float2(Zt[e].r, Zt[e].i);
    #pragma unroll
    for (int e = 0; e < 4; ++e) P[8+e] = make_float2(-Yt[e].r, -Yt[e].i);
  } else if (tid >= 64 && tid < 69) {             // wave 1
    int q = tid - 64;
    Cf U2[4]; fusedU(params + 37 + 3*q, U2);
    #pragma unroll
    for (int e = 0; e < 4; ++e) U2l[q*4+e] = make_float2(U2[e].r, U2[e].i);
  } else if (tid >= 128 && tid < 136) {           // wave 2
    int i = tid - 128;
    float th = (i < 4) ? params[15 + i] : params[52 + (i - 4)];
    crxcl[i] = __cosf(0.5f*th); crxsl[i] = __sinf(0.5f*th);
  } else if (tid >= 192 && tid < 198) {           // wave 3
    int k = tid - 192;
    Cf Ua[4], Ub[4], W[4];
    fusedU(params + 19 + 3*k, Ua);
    fusedU(params + 56 + 3*k, Ub);
    mm2(Ub, Ua, W);
    #pragma unroll
    for (int e = 0; e < 4; ++e) { Wl[k*8+2*e] = W[e].r; Wl[k*8+2*e+1] = W[e].i; }
  }
  __syncthreads();

  // ============ V build: DPP gate application (threads 0..255) ============
  if (tid < 256) {
    const int quad = tid & 7, col = tid >> 3;
    const int vb2 = quad & 1, vb3 = (quad >> 1) & 1, vb4 = quad >> 2;
    Cf A[4];
    #pragma unroll
    for (int r = 0; r < 4; ++r)
      A[r] = { ((quad<<2)|r) == col ? 1.f : 0.f, 0.f };
    Cf U2g[5][4];
    #pragma unroll
    for (int q = 0; q < 5; ++q)
      #pragma unroll
      for (int e = 0; e < 4; ++e)
        U2g[q][e] = { U2l[q*4+e].x, U2l[q*4+e].y };
    float c_[8], s_[8];
    #pragma unroll
    for (int g = 0; g < 8; ++g) { c_[g] = crxcl[g]; s_[g] = crxsl[g]; }
    lane_crx<2>(A, c_[0], s_[0], vb4);
    lane_crx<1>(A, c_[1], s_[1], vb3);
    reg_crx_b1 (A, c_[2], s_[2], vb2);
    reg_crx_b0c1(A, c_[3], s_[3]);
    lane_u<4>(A, U2g[0], vb4);
    lane_u<2>(A, U2g[1], vb3);
    lane_u<1>(A, U2g[2], vb2);
    reg_u_b1 (A, U2g[3]);
    reg_u_b0 (A, U2g[4]);
    lane_crx<2>(A, c_[4], s_[4], vb4);
    lane_crx<1>(A, c_[5], s_[5], vb3);
    reg_crx_b1 (A, c_[6], s_[6], vb2);
    reg_crx_b0c1(A, c_[7], s_[7]);
    #pragma unroll
    for (int r = 0; r < 4; ++r)
      Vp[((quad<<2)|r)*32 + col] = make_float2(A[r].r, A[r].i);
  }
  __syncthreads();

  // ====== Phase C + stage 1, i-split across halves (linear in G) ==========
  {
    const int jk = tid & 255;
    const int jt = jk >> 4, kt = jk & 15;
    const int half = tid >> 8;
    const int ibase = half << 4;
    float2 Tacc[2][2], Bacc[4][2][2];
    #pragma unroll
    for (int a = 0; a < 2; ++a)
      #pragma unroll
      for (int c2 = 0; c2 < 2; ++c2) {
        Tacc[a][c2] = make_float2(0.f, 0.f);
        #pragma unroll
        for (int mb = 0; mb < 4; ++mb) Bacc[mb][a][c2] = make_float2(0.f, 0.f);
      }
    #pragma unroll
    for (int ii = 0; ii < 16; ++ii) {
      const int i = ibase + ii;
      float4 vj = Vp4[i*16 + jt], vk = Vp4[i*16 + kt];
      float2 vj0{vj.x,vj.y}, vj1{vj.z,vj.w}, vk0{vk.x,vk.y}, vk1{vk.z,vk.w};
      float2 p[2][2] = {{conjmul(vj0,vk0), conjmul(vj0,vk1)},
                        {conjmul(vj1,vk0), conjmul(vj1,vk1)}};
      #pragma unroll
      for (int a = 0; a < 2; ++a)
        #pragma unroll
        for (int c2 = 0; c2 < 2; ++c2) {
          Tacc[a][c2].x += p[a][c2].x; Tacc[a][c2].y += p[a][c2].y;
        }
      #pragma unroll
      for (int mb = 0; mb < 4; ++mb)
        if (ii & (8 >> mb)) {
          #pragma unroll
          for (int a = 0; a < 2; ++a)
            #pragma unroll
            for (int c2 = 0; c2 < 2; ++c2) {
              Bacc[mb][a][c2].x += p[a][c2].x; Bacc[mb][a][c2].y += p[a][c2].y;
            }
        }
    }
    float2 P4[12];
    #pragma unroll
    for (int e = 0; e < 12; ++e) P4[e] = Pl[4*12 + e];
    const float sgn0 = half ? -1.f : 1.f;
    float2 acc[15];
    #pragma unroll
    for (int m = 0; m < 5; ++m) {
      float2 G[2][2];
      #pragma unroll
      for (int a = 0; a < 2; ++a)
        #pragma unroll
        for (int c2 = 0; c2 < 2; ++c2) {
          float2 t = Tacc[a][c2];
          if (m == 0) G[a][c2] = make_float2(sgn0*t.x, sgn0*t.y);
          else {
            float2 bv = Bacc[m-1][a][c2];
            G[a][c2] = make_float2(t.x - 2.f*bv.x, t.y - 2.f*bv.y);
          }
        }
      #pragma unroll
      for (int s = 0; s < 3; ++s) {
        float ax = 0.f, ay = 0.f;
        #pragma unroll
        for (int a = 0; a < 2; ++a)
          #pragma unroll
          for (int bb = 0; bb < 2; ++bb) {
            float2 g = G[a][bb];
            float2 p = P4[s*4 + bb*2 + a];
            ax += g.x*p.x - g.y*p.y;
            ay += g.x*p.y + g.y*p.x;
          }
        acc[m*3 + s] = make_float2(ax, ay);
      }
    }
    if (half) {
      #pragma unroll
      for (int e = 0; e < 15; ++e) A1[e*256 + jk] = acc[e];
    }
    __syncthreads();
    if (!half) {
      #pragma unroll
      for (int e = 0; e < 15; ++e) {
        float2 v = A1[e*256 + jk];
        A1[e*256 + jk] = make_float2(v.x + acc[e].x, v.y + acc[e].y);
      }
    }
  }
  __syncthreads();

  stageK<3, 8>(A1, A2, Pl + 3*12, tid);  __syncthreads();
  stageK<9, 4>(A2, A3, Pl + 2*12, tid);  __syncthreads();
  stageK<27,2>(A3, A4, Pl + 1*12, tid);  __syncthreads();
  // final: peel qubit 0, real part, fold 1/32  (radians basis)
  for (int tau = tid; tau < 5*256; tau += BLOCK) {
    int n = tau & 255, m = tau >> 8;
    float val = 0.f;
    if (n < 243) {
      int t = n % 81, s = n / 81;
      const float2* Sb = A4 + (m*81 + t)*4;
      const float2* Pm = Pl + s*4;
      float ax = 0.f;
      #pragma unroll
      for (int a = 0; a < 2; ++a)
        #pragma unroll
        for (int bb = 0; bb < 2; ++bb) {
          float2 g = Sb[a*2 + bb];
          float2 p = Pm[bb*2 + a];
          ax += g.x*p.x - g.y*p.y;
        }
      val = ax * 0.03125f;
    }
    coefL[tau] = val;
  }
  __syncthreads();

  // ================= main work =============================================
  const int w = tid >> 6, lane = tid & 63;
  if (w == 0) {
    // ---- hidden recurrence: 243-monomial map, op_sel trig broadcast ----
    v2f sAp[2][5], sBp[2][5], sCp[2][5], cfp[5][2];
    #pragma unroll
    for (int s = 0; s < 2; ++s) {
      #pragma unroll
      for (int half = 0; half < 2; ++half) {
        int n = (2*s + half)*64 + lane;
        int nn = (n < 243) ? n : 0;
        int d0 = nn/81; int rm = nn - d0*81;
        int d1 = rm/27; rm -= d1*27;
        int d2 = rm/9;  rm -= d2*9;
        int d3 = rm/3;  int d4 = rm - d3*3;
        int dq[5] = {d0, d1, d2, d3, d4};
        #pragma unroll
        for (int q = 0; q < 5; ++q) {
          if (half == 0) {
            sAp[s][q].x = (dq[q] == 0) ? 1.f : 0.f;
            sBp[s][q].x = (dq[q] == 1) ? 1.f : 0.f;
            sCp[s][q].x = (dq[q] == 2) ? 1.f : 0.f;
          } else {
            sAp[s][q].y = (dq[q] == 0) ? 1.f : 0.f;
            sBp[s][q].y = (dq[q] == 1) ? 1.f : 0.f;
            sCp[s][q].y = (dq[q] == 2) ? 1.f : 0.f;
          }
        }
      }
    }
    #pragma unroll
    for (int m = 0; m < 5; ++m) {
      cfp[m][0].x = coefL[m*256 + lane];
      cfp[m][0].y = coefL[m*256 + lane + 64];
      cfp[m][1].x = coefL[m*256 + lane + 128];
      cfp[m][1].y = coefL[m*256 + lane + 192];
    }
    // poly constants (|x| <= ~1.05): sin deg-7, cos deg-8
    const v2f cS7 = {-1.98412698e-4f, -1.98412698e-4f};
    const v2f cS5 = {8.33333333e-3f, 8.33333333e-3f};
    const v2f cS3 = {-0.166666667f, -0.166666667f};
    const v2f cS1 = {1.f, 1.f};
    const v2f cC8 = {2.48015873e-5f, 2.48015873e-5f};
    const v2f cC6 = {-1.38888889e-3f, -1.38888889e-3f};
    const v2f cC4 = {4.16666667e-2f, 4.16666667e-2f};
    const v2f cC2 = {-0.5f, -0.5f};
    const v2f cC0 = {1.f, 1.f};

    const float* hp = hin + b*5;
    float h0 = hp[0], h1 = hp[1], h2 = hp[2], h3 = hp[3], h4 = hp[4];
    #pragma unroll 1
    for (int t = 0; t < TSTEPS; ++t) {
      // ---- packed polynomial sin/cos on 3 pairs ----
      v2f x01 = {h0, h1}, x23 = {h2, h3}, x45 = {h4, h4};
      v2f x2a = pk_mul(x01, x01), x2b = pk_mul(x23, x23), x2c = pk_mul(x45, x45);
      v2f ps, pc;
      ps = pk_fma(x2a, cS7, cS5); ps = pk_fma(x2a, ps, cS3); ps = pk_fma(x2a, ps, cS1);
      v2f S01 = pk_mul(x01, ps);
      ps = pk_fma(x2b, cS7, cS5); ps = pk_fma(x2b, ps, cS3); ps = pk_fma(x2b, ps, cS1);
      v2f S23 = pk_mul(x23, ps);
      ps = pk_fma(x2c, cS7, cS5); ps = pk_fma(x2c, ps, cS3); ps = pk_fma(x2c, ps, cS1);
      v2f S45 = pk_mul(x45, ps);
      pc = pk_fma(x2a, cC8, cC6); pc = pk_fma(x2a, pc, cC4); pc = pk_fma(x2a, pc, cC2);
      v2f C01 = pk_fma(x2a, pc, cC0);
      pc = pk_fma(x2b, cC8, cC6); pc = pk_fma(x2b, pc, cC4); pc = pk_fma(x2b, pc, cC2);
      v2f C23 = pk_fma(x2b, pc, cC0);
      pc = pk_fma(x2c, cC8, cC6); pc = pk_fma(x2c, pc, cC4); pc = pk_fma(x2c, pc, cC2);
      v2f C45 = pk_fma(x2c, pc, cC0);

      v2f monoP[2];
      #pragma unroll
      for (int s = 0; s < 2; ++s) {
        v2f f0 = pk_fma_bl(sBp[s][0], C01, pk_fma_bl(sCp[s][0], S01, sAp[s][0]));
        v2f f1 = pk_fma_bh(sBp[s][1], C01, pk_fma_bh(sCp[s][1], S01, sAp[s][1]));
        v2f f2 = pk_fma_bl(sBp[s][2], C23, pk_fma_bl(sCp[s][2], S23, sAp[s][2]));
        v2f f3 = pk_fma_bh(sBp[s][3], C23, pk_fma_bh(sCp[s][3], S23, sAp[s][3]));
        v2f f4 = pk_fma(sBp[s][4], C45, pk_fma(sCp[s][4], S45, sAp[s][4]));
        monoP[s] = pk_mul(pk_mul(pk_mul(f0, f1), pk_mul(f2, f3)), f4);
      }
      // per-m dots, collapse, then 5-chain single-asm reduction
      v2f t0 = pk_fma(monoP[1], cfp[0][1], pk_mul(monoP[0], cfp[0][0]));
      v2f t1 = pk_fma(monoP[1], cfp[1][1], pk_mul(monoP[0], cfp[1][0]));
      v2f t2 = pk_fma(monoP[1], cfp[2][1], pk_mul(monoP[0], cfp[2][0]));
      v2f t3 = pk_fma(monoP[1], cfp[3][1], pk_mul(monoP[0], cfp[3][0]));
      v2f t4 = pk_fma(monoP[1], cfp[4][1], pk_mul(monoP[0], cfp[4][0]));
      float r0 = t0.x + t0.y, r1 = t1.x + t1.y, r2 = t2.x + t2.y,
            r3 = t3.x + t3.y, r4 = t4.x + t4.y;
      wave_red5(r0, r1, r2, r3, r4);
      h0 = __int_as_float(__builtin_amdgcn_readlane(__float_as_int(r0), 63));
      h1 = __int_as_float(__builtin_amdgcn_readlane(__float_as_int(r1), 63));
      h2 = __int_as_float(__builtin_amdgcn_readlane(__float_as_int(r2), 63));
      h3 = __int_as_float(__builtin_amdgcn_readlane(__float_as_int(r3), 63));
      h4 = __int_as_float(__builtin_amdgcn_readlane(__float_as_int(r4), 63));
    }
    if (lane < 5) {
      float hv = (lane==0) ? h0 : (lane==1) ? h1 : (lane==2) ? h2
               : (lane==3) ? h3 : h4;
      out[BATCH*TSTEPS*6 + b*5 + lane] = hv;
    }
  } else if (w == 1 && lane < TSTEPS) {
    // ---- visible outputs (pure function of x; W precomputed in LDS) ----
    const float* xp = x + (size_t)b*(TSTEPS*FEAT) + lane*FEAT;
    const float4* xp4 = (const float4*)xp;
    float4 vv[15];
    #pragma unroll
    for (int i2 = 0; i2 < 15; ++i2) vv[i2] = xp4[i2];
    float el[60];
    #pragma unroll
    for (int i2 = 0; i2 < 15; ++i2) {
      el[4*i2+0] = vv[i2].x; el[4*i2+1] = vv[i2].y;
      el[4*i2+2] = vv[i2].z; el[4*i2+3] = vv[i2].w;
    }
    float pooled[6];
    #pragma unroll
    for (int k = 0; k < 6; ++k) {
      float s = 0.f;
      #pragma unroll
      for (int f = 0; f < 10; ++f) s += el[k*10 + f];
      pooled[k] = s * 0.1f;
    }
    float mn = pooled[0], mx = pooled[0];
    #pragma unroll
    for (int v2 = 1; v2 < 6; ++v2) {
      mn = fminf(mn, pooled[v2]); mx = fmaxf(mx, pooled[v2]);
    }
    float* op = out + (size_t)b*(TSTEPS*6) + lane*6;
    #pragma unroll
    for (int k = 0; k < 6; ++k) {
      float W0r = Wl[k*8+0], W0i = Wl[k*8+1], W1r = Wl[k*8+2], W1i = Wl[k*8+3];
      float W2r = Wl[k*8+4], W2i = Wl[k*8+5], W3r = Wl[k*8+6], W3i = Wl[k*8+7];
      float ang = TWO_PI_F * (pooled[k] - mn) / (mx - mn + 1e-8f);
      float ch = __cosf(0.5f*ang), sh = __sinf(0.5f*ang);
      float v0r = W0r*ch + W1i*sh, v0i = W0i*ch - W1r*sh;
      float v1r = W2r*ch + W3i*sh, v1i = W2i*ch - W3r*sh;
      op[k] = (v0r*v0r + v0i*v0i) - (v1r*v1r + v1i*v1i);
    }
  }
}

extern "C" void kernel_launch(void* const* d_in, const int* in_sizes, int n_in,
                              void* d_out, int out_size, void* d_ws, size_t ws_size,
                              hipStream_t stream) {
  const float* x      = (const float*)d_in[0];
  const float* hidden = (const float*)d_in[1];
  const float* params = (const float*)d_in[2];
  float* out          = (float*)d_out;
  qrnn_kernel<<<dim3(BATCH), dim3(BLOCK), 0, stream>>>(x, hidden, params, out);
}